// Round 13
// baseline (1071.177 us; speedup 1.0000x reference)
//
#include <hip/hip_runtime.h>
#include <hip/hip_cooperative_groups.h>
#include <math.h>

namespace cg = cooperative_groups;

#define NB    64        // graphs
#define NPER  1024      // nodes per graph
#define NTOT  65536     // total nodes
#define ETOT  1048576   // edges
#define FEAT  64
#define HID   128
#define KSEL  10
#define MAXDEG 64       // CSR slot capacity per node (max in-degree ~40)

// ===================== FUSED COOPERATIVE PATH (512 blocks x 512 threads) ============
// 64 KB static LDS/block => exactly 2 blocks/CU by LDS => cooperative residency for
// grid=512 guaranteed as long as VGPR<=128 (launch_bounds(512,4), trivially met).
// Phases (grid.sync between): csr(+fvec+part0) -> agg0 -> gemm0(+maxpool) ->
// {agg128; gemm}(conv1 x2, conv2 w/ inline glob + z=..@W3) -> smask.
// Layouts: Z chunk-major C[c][v][16]; AT feature-major [k][v];
//          colp pair-packed slot-major u32 = (slot2p+1<<16)|slot2p.

__device__ __forceinline__ void agg_gather512(const float4* __restrict__ sy4,
                                              const unsigned int* __restrict__ colp,
                                              const int* __restrict__ cnt,
                                              float* __restrict__ P,
                                              int gbase, int cbase, int vbase, int npass) {
    int t = threadIdx.x;
    int f4 = t & 3;
    int vl = t >> 2;                        // 0..127
#pragma unroll 1
    for (int pass = 0; pass < npass; ++pass) {
        int v = vbase + pass * 128 + vl;
        int gv = gbase + v;
        int n = cnt[gv];
        float dv = rsqrtf((float)n + 1.0f);
        const unsigned int* ip = colp + gv;
        float4 a = sy4[v * 4 + f4];         // self term (pre-scaled by dinv)
        int np = n >> 1;
        for (int i = 0; i < np; ++i) {
            unsigned int pw = ip[(size_t)i * NTOT];
            float4 ya = sy4[(int)(pw & 0xFFFF) * 4 + f4];
            float4 yb = sy4[(int)(pw >> 16) * 4 + f4];
            a.x += ya.x + yb.x; a.y += ya.y + yb.y;
            a.z += ya.z + yb.z; a.w += ya.w + yb.w;
        }
        if (n & 1) {
            float4 ya = sy4[(int)(ip[(size_t)np * NTOT] & 0xFFFF) * 4 + f4];
            a.x += ya.x; a.y += ya.y; a.z += ya.z; a.w += ya.w;
        }
        a.x *= dv; a.y *= dv; a.z *= dv; a.w *= dv;
        int krow = cbase + f4 * 4;          // feature-major write
        P[(size_t)(krow + 0) * NTOT + gv] = a.x;
        P[(size_t)(krow + 1) * NTOT + gv] = a.y;
        P[(size_t)(krow + 2) * NTOT + gv] = a.z;
        P[(size_t)(krow + 3) * NTOT + gv] = a.w;
    }
}

// gemm phase: 128x128 tile per block (512 blocks cover 65536 rows), 8x4 micro-tile.
// mode 0: plain Z out; mode 1: +per-graph col-max (part); mode 2: inline glob,
// z = dinv*(relu(.)@W3), no dense out.
__device__ __forceinline__ void gemm_phase512(const float* __restrict__ AT,
                                              const float* __restrict__ W,
                                              const float* __restrict__ bias,
                                              float* __restrict__ outZ, int K, int mode,
                                              const float* __restrict__ fvec,
                                              const float* __restrict__ Wf,
                                              const float* __restrict__ bfv,
                                              const float* __restrict__ W2b,
                                              float* __restrict__ part,
                                              const float* __restrict__ W3,
                                              const int* __restrict__ cnt,
                                              float* __restrict__ zout,
                                              float* smem) {
    int t = threadIdx.x;
    int row0 = blockIdx.x * 128;
    float* At = smem;               // 32 x 132 = 4224
    float* Wt = smem + 4224;        // 32 x 132 -> ends 8448
    float* mp  = smem + 8448;
    float* gl  = smem + 8576;
    float* gpr = smem + 8704;       // ends 8832
    int tx = t & 31;                // col group: cols tx*4..+3
    int ty = t >> 5;                // row group 0..15: rows ty*8..+7
    int g = row0 >> 10;

    if (mode == 2) {                // inline glob: gproj for this block's graph
        if (t < 128) mp[t] = part[g * 128 + t];
        __syncthreads();
        if (t < 128) {
            float a = bfv[t];
            for (int k = 0; k < 128; ++k) a += mp[k] * Wf[k * 128 + t];
            gl[t] = a;
        }
        __syncthreads();
        if (t < 128) {
            float a = 0.f;
            for (int k = 0; k < 128; ++k) a += gl[k] * W2b[k * 128 + t];
            gpr[t] = a;
        }
        __syncthreads();
    }

    float acc[8][4];
#pragma unroll
    for (int i = 0; i < 8; ++i)
#pragma unroll
        for (int j = 0; j < 4; ++j) acc[i][j] = 0.f;

    for (int kt = 0; kt < K; kt += 32) {
#pragma unroll
        for (int p = 0; p < 2; ++p) {   // stage A: 32 k x 128 rows (b128 copies)
            int idx = p * 512 + t;
            int kk = idx >> 5;
            int r4 = (idx & 31) * 4;
            *(float4*)&At[kk * 132 + r4] =
                *(const float4*)&AT[(size_t)(kt + kk) * NTOT + row0 + r4];
        }
#pragma unroll
        for (int p = 0; p < 2; ++p) {   // stage W: 32 k x 128 cols
            int idx = p * 512 + t;
            int kk = idx >> 5;
            int c4 = (idx & 31) * 4;
            *(float4*)&Wt[kk * 132 + c4] =
                *(const float4*)&W[(size_t)(kt + kk) * 128 + c4];
        }
        __syncthreads();
#pragma unroll
        for (int k = 0; k < 32; ++k) {
            float4 a0 = *(const float4*)&At[k * 132 + ty * 8];
            float4 a1 = *(const float4*)&At[k * 132 + ty * 8 + 4];
            float4 w  = *(const float4*)&Wt[k * 132 + tx * 4];
            float a[8] = {a0.x, a0.y, a0.z, a0.w, a1.x, a1.y, a1.z, a1.w};
#pragma unroll
            for (int i = 0; i < 8; ++i) {
                acc[i][0] += a[i] * w.x;
                acc[i][1] += a[i] * w.y;
                acc[i][2] += a[i] * w.z;
                acc[i][3] += a[i] * w.w;
            }
        }
        __syncthreads();
    }

    float b[4];
#pragma unroll
    for (int j = 0; j < 4; ++j) b[j] = bias[tx * 4 + j];

    if (mode == 2) {
        float fr[8], gp[4], w3[4], zp[8];
#pragma unroll
        for (int i = 0; i < 8; ++i) fr[i] = fvec[row0 + ty * 8 + i];
#pragma unroll
        for (int j = 0; j < 4; ++j) { gp[j] = gpr[tx * 4 + j]; w3[j] = W3[tx * 4 + j]; }
#pragma unroll
        for (int i = 0; i < 8; ++i) {
            float zpi = 0.f;
#pragma unroll
            for (int j = 0; j < 4; ++j) {
                float v = fmaxf(acc[i][j] + b[j] + fr[i] * gp[j], 0.f);
                zpi += v * w3[j];
            }
            zp[i] = zpi;
        }
        float* zsm = smem;          // 128 x 32 = 4096
        __syncthreads();
#pragma unroll
        for (int i = 0; i < 8; ++i) zsm[(ty * 8 + i) * 32 + tx] = zp[i];
        __syncthreads();
        if (t < 128) {
            float s = 0.f;
#pragma unroll
            for (int xg = 0; xg < 32; ++xg) s += zsm[t * 32 + xg];
            zout[row0 + t] = s * rsqrtf((float)cnt[row0 + t] + 1.0f);
        }
    } else {
        float dvs[8], m[4];
#pragma unroll
        for (int i = 0; i < 8; ++i) dvs[i] = rsqrtf((float)cnt[row0 + ty * 8 + i] + 1.0f);
#pragma unroll
        for (int j = 0; j < 4; ++j) m[j] = 0.f;   // relu floor
        int cc = tx >> 2, off = (tx & 3) * 4;
#pragma unroll
        for (int i = 0; i < 8; ++i) {
            int r = row0 + ty * 8 + i;
            float o[4];
#pragma unroll
            for (int j = 0; j < 4; ++j) {
                float v = fmaxf(acc[i][j] + b[j], 0.f);
                if (mode == 1) m[j] = fmaxf(m[j], v);
                o[j] = v * dvs[i];
            }
            *(float4*)&outZ[((size_t)cc * NTOT + r) * 16 + off] =
                make_float4(o[0], o[1], o[2], o[3]);
        }
        if (mode == 1) {   // col-max across 16 row-groups, then atomicMax
            float* sm = smem;       // 16 x 128 = 2048
            __syncthreads();
#pragma unroll
            for (int j = 0; j < 4; ++j) sm[ty * 128 + tx * 4 + j] = m[j];
            __syncthreads();
            for (int s = 8; s >= 1; s >>= 1) {
                if (ty < s) {
#pragma unroll
                    for (int j = 0; j < 4; ++j) {
                        int idx = ty * 128 + tx * 4 + j;
                        sm[idx] = fmaxf(sm[idx], sm[(ty + s) * 128 + tx * 4 + j]);
                    }
                }
                __syncthreads();
            }
            if (ty == 0) {
                int* pp = (int*)&part[(size_t)g * 128 + tx * 4];
#pragma unroll
                for (int j = 0; j < 4; ++j)
                    atomicMax(pp + j, __float_as_int(sm[tx * 4 + j]));
            }
        }
    }
}

__global__ __launch_bounds__(512, 4) void fused_k(
        const float* __restrict__ x,
        const int* __restrict__ esrc, const int* __restrict__ edst,
        const float* __restrict__ W0, const float* __restrict__ b0,
        const float* __restrict__ W1, const float* __restrict__ b1,
        const float* __restrict__ Wf, const float* __restrict__ bf,
        const float* __restrict__ W2, const float* __restrict__ b2,
        const float* __restrict__ W3, const float* __restrict__ b3,
        float* __restrict__ out, char* __restrict__ ws) {
    __shared__ __align__(16) float smem[16384];   // 64 KB -> 2 blocks/CU by LDS
    cg::grid_group grid = cg::this_grid();
    int t = threadIdx.x;

    int*            cnt   = (int*)ws;
    unsigned short* col16 = (unsigned short*)(ws + (size_t)NTOT * 4);
    float*          fvec  = (float*)(ws + (size_t)NTOT * 4 + (size_t)NTOT * MAXDEG * 2);
    float*          P     = fvec + NTOT;                    // AT, feature-major
    float*          Q     = P + (size_t)NTOT * 128;         // Z, chunk-major
    float*          part  = Q + (size_t)NTOT * 128;
    float*          z     = part + NB * 128;
    const unsigned int* colp = (const unsigned int*)col16;

    // ---- P1: CSR build (LDS atomics) + cnt + fvec + part zero; blocks 0..63 -------
    if (blockIdx.x < NB) {
        int* scnt = (int*)smem;
        float* sdv = smem + 1024;
        int g = blockIdx.x;
        int nbase = g << 10;
        scnt[t] = 0; scnt[t + 512] = 0;
        __syncthreads();
        int ebase = g * (NPER * 16);
#pragma unroll 1
        for (int j = 0; j < 32; ++j) {
            int e = ebase + j * 512 + t;
            int d = edst[e] & (NPER - 1);
            int s = esrc[e] & (NPER - 1);
            int pos = atomicAdd(&scnt[d], 1);
            col16[((size_t)(pos >> 1) * NTOT + nbase + d) * 2 + (pos & 1)] =
                (unsigned short)s;
        }
        __syncthreads();
#pragma unroll
        for (int h = 0; h < 2; ++h) {
            int v = t + h * 512;
            int n = scnt[v];
            cnt[nbase + v] = n;
            sdv[v] = rsqrtf((float)n + 1.0f);
        }
        if (t < 128) part[g * 128 + t] = 0.f;   // atomicMax base (relu>=0)
        __syncthreads();
#pragma unroll 1
        for (int h = 0; h < 2; ++h) {
            int v = t + h * 512;
            int n = scnt[v];
            float dv = sdv[v];
            float acc = dv;
            const unsigned int* ip = colp + nbase + v;
            int np = n >> 1;
            for (int i = 0; i < np; ++i) {
                unsigned int pw = ip[(size_t)i * NTOT];
                acc += sdv[pw & 0xFFFF] + sdv[pw >> 16];
            }
            if (n & 1) acc += sdv[ip[(size_t)np * NTOT] & 0xFFFF];
            fvec[nbase + v] = dv * acc;
        }
    }
    grid.sync();

    // ---- P2: agg0 over x (64-wide): (graph, chunk 0..3, node-half) ----------------
    {
        float4* sy4 = (float4*)smem;
        int g = blockIdx.x >> 3;
        int s = blockIdx.x & 7;
        int c = s >> 1, h = s & 1;
        int gbase = g << 10;
#pragma unroll
        for (int j = 0; j < 8; ++j) {
            int fl = j * 512 + t;
            int v = fl >> 2, q = fl & 3;
            float dvv = rsqrtf((float)cnt[gbase + v] + 1.0f);
            float4 zv = *(const float4*)&x[(size_t)(gbase + v) * FEAT + c * 16 + q * 4];
            zv.x *= dvv; zv.y *= dvv; zv.z *= dvv; zv.w *= dvv;
            sy4[fl] = zv;
        }
        __syncthreads();
        agg_gather512(sy4, colp, cnt, P, gbase, c * 16, h * 512, 4);
    }
    grid.sync();

    // ---- P3: gemm0 (K=64) + maxpool->part -----------------------------------------
    gemm_phase512(P, W0, b0, Q, 64, 1, nullptr, nullptr, nullptr, nullptr,
                  part, nullptr, cnt, nullptr, smem);
    grid.sync();

    // ---- conv1 x2 + conv2: {agg128; gemm} x3 --------------------------------------
#pragma unroll 1
    for (int layer = 0; layer < 3; ++layer) {
        {   // agg128: Q -> P, one (g, c) per block
            float4* sy4 = (float4*)smem;
            int g = blockIdx.x >> 3;
            int c = blockIdx.x & 7;
            int gbase = g << 10;
            const float4* Zg4 = (const float4*)(Q + ((size_t)c * NTOT + gbase) * 16);
#pragma unroll
            for (int j = 0; j < 8; ++j) sy4[j * 512 + t] = Zg4[j * 512 + t];
            __syncthreads();
            agg_gather512(sy4, colp, cnt, P, gbase, c * 16, 0, 8);
        }
        grid.sync();
        if (layer < 2)
            gemm_phase512(P, W1, b1, Q, 128, 0, nullptr, nullptr, nullptr, nullptr,
                          nullptr, nullptr, cnt, nullptr, smem);
        else
            gemm_phase512(P, W2, b2, nullptr, 128, 2, fvec, Wf, bf, W2 + 128 * 128,
                          part, W3, cnt, z, smem);
        grid.sync();
    }

    // ---- P10: fused scalar-agg + top-K mask; blocks 0..63 -------------------------
    if (blockIdx.x < NB) {
        float* sz  = smem;             // 1024
        float* sl  = smem + 1024;      // 1024
        float* slo = smem + 2048;      // 1024
        float* rv  = smem + 3072;      // 512
        int*   ri  = (int*)(smem + 3584);  // 512
        int g = blockIdx.x;
        int base = g << 10;
        sz[t] = z[base + t]; sz[t + 512] = z[base + t + 512];
        __syncthreads();
        float bb = b3[0];
#pragma unroll 1
        for (int h = 0; h < 2; ++h) {
            int v = t + h * 512;
            int gv = base + v;
            int n = cnt[gv];
            float dv = rsqrtf((float)n + 1.0f);
            float acc = sz[v];
            const unsigned int* ip = colp + gv;
            int np = n >> 1;
            for (int j = 0; j < np; ++j) {
                unsigned int pw = ip[(size_t)j * NTOT];
                acc += sz[pw & 0xFFFF] + sz[pw >> 16];
            }
            if (n & 1) acc += sz[ip[(size_t)np * NTOT] & 0xFFFF];
            float lg = acc * dv + bb;
            sl[v] = lg; slo[v] = lg;
        }
        __syncthreads();
        for (int pass = 0; pass < KSEL; ++pass) {
            float bv = sl[t]; int bi = t;
            if (sl[t + 512] > bv) { bv = sl[t + 512]; bi = t + 512; }
            rv[t] = bv; ri[t] = bi;
            __syncthreads();
            for (int s = 256; s > 0; s >>= 1) {
                if (t < s) {
                    if (rv[t + s] > rv[t]) { rv[t] = rv[t + s]; ri[t] = ri[t + s]; }
                }
                __syncthreads();
            }
            if (t == 0) { smem[4096] = rv[0]; sl[ri[0]] = -INFINITY; }
            __syncthreads();
        }
        float th = smem[4096];
        out[base + t] = (slo[t] >= th) ? 1.f : 0.f;
        out[base + t + 512] = (slo[t + 512] >= th) ? 1.f : 0.f;
    }
}

// ===================== FALLBACK MULTI-KERNEL PATH (proven R10, 361 us) ==============
__global__ __launch_bounds__(256) void init_k(int* __restrict__ cnt,
                                              float* __restrict__ part) {
    int v = blockIdx.x * 256 + threadIdx.x;
    cnt[v] = 0;
    if (v < NB * 128) part[v] = 0.f;
}

__global__ __launch_bounds__(256) void csr_k(const int* __restrict__ src,
                                             const int* __restrict__ dst,
                                             int* __restrict__ cnt,
                                             unsigned short* __restrict__ col16) {
    int e = blockIdx.x * 256 + threadIdx.x;
    if (e >= ETOT) return;
    int d = dst[e];
    int s = src[e];
    int pos = atomicAdd(&cnt[d], 1);
    col16[((size_t)(pos >> 1) * NTOT + d) * 2 + (pos & 1)] =
        (unsigned short)(s & (NPER - 1));
}

__global__ __launch_bounds__(1024) void agg_k(const float* __restrict__ Z,
                                              const float* __restrict__ x,
                                              const unsigned int* __restrict__ colp,
                                              const int* __restrict__ cnt,
                                              float* __restrict__ outAT,
                                              int cshift,
                                              float* __restrict__ fvec) {
    __shared__ float4 sy4[4096];
    int t = threadIdx.x;
    int g = blockIdx.x >> cshift;
    int c = blockIdx.x & ((1 << cshift) - 1);
    int gbase = g << 10;
    if (x) {
#pragma unroll
        for (int j = 0; j < 4; ++j) {
            int fl = j * 1024 + t;
            int v = fl >> 2, q = fl & 3;
            float dvv = rsqrtf((float)cnt[gbase + v] + 1.0f);
            float4 zv = *(const float4*)&x[(size_t)(gbase + v) * FEAT + c * 16 + q * 4];
            zv.x *= dvv; zv.y *= dvv; zv.z *= dvv; zv.w *= dvv;
            sy4[fl] = zv;
        }
    } else {
        const float4* Zg4 = (const float4*)(Z + ((size_t)c * NTOT + gbase) * 16);
#pragma unroll
        for (int j = 0; j < 4; ++j) sy4[j * 1024 + t] = Zg4[j * 1024 + t];
    }
    __syncthreads();
    int f4 = t & 3;
    int vl = t >> 2;
#pragma unroll 1
    for (int pass = 0; pass < 4; ++pass) {
        int v = pass * 256 + vl;
        int gv = gbase + v;
        int n = cnt[gv];
        float dv = rsqrtf((float)n + 1.0f);
        const unsigned int* ip = colp + gv;
        float4 a = sy4[v * 4 + f4];
        int np = n >> 1;
        for (int i = 0; i < np; ++i) {
            unsigned int pw = ip[(size_t)i * NTOT];
            float4 ya = sy4[(int)(pw & 0xFFFF) * 4 + f4];
            float4 yb = sy4[(int)(pw >> 16) * 4 + f4];
            a.x += ya.x + yb.x; a.y += ya.y + yb.y;
            a.z += ya.z + yb.z; a.w += ya.w + yb.w;
        }
        if (n & 1) {
            float4 ya = sy4[(int)(ip[(size_t)np * NTOT] & 0xFFFF) * 4 + f4];
            a.x += ya.x; a.y += ya.y; a.z += ya.z; a.w += ya.w;
        }
        a.x *= dv; a.y *= dv; a.z *= dv; a.w *= dv;
        int krow = c * 16 + f4 * 4;
        outAT[(size_t)(krow + 0) * NTOT + gv] = a.x;
        outAT[(size_t)(krow + 1) * NTOT + gv] = a.y;
        outAT[(size_t)(krow + 2) * NTOT + gv] = a.z;
        outAT[(size_t)(krow + 3) * NTOT + gv] = a.w;
    }
    if (fvec && c == 0) {
        __syncthreads();
        float* sdv = (float*)sy4;
        float dv = rsqrtf((float)cnt[gbase + t] + 1.0f);
        sdv[t] = dv;
        __syncthreads();
        int n = cnt[gbase + t];
        float acc = dv;
        const unsigned int* ip = colp + gbase + t;
        int np = n >> 1;
        for (int i = 0; i < np; ++i) {
            unsigned int pw = ip[(size_t)i * NTOT];
            acc += sdv[pw & 0xFFFF] + sdv[pw >> 16];
        }
        if (n & 1) acc += sdv[ip[(size_t)np * NTOT] & 0xFFFF];
        fvec[gbase + t] = dv * acc;
    }
}

__global__ __launch_bounds__(256, 4) void gemm_k(const float* __restrict__ AT,
                                                 const float* __restrict__ W,
                                                 const float* __restrict__ bias,
                                                 float* __restrict__ outZ,
                                                 int K,
                                                 const float* __restrict__ fvec,
                                                 const float* __restrict__ gproj,
                                                 float* __restrict__ part,
                                                 const float* __restrict__ W3,
                                                 const int* __restrict__ cnt,
                                                 float* __restrict__ zout) {
    __shared__ float At[32][68];
    __shared__ float Wt[32][132];
    int t = threadIdx.x;
    int row0 = blockIdx.x * 64;
    int tx = t & 31;
    int ty = t >> 5;
    float acc[8][4];
#pragma unroll
    for (int i = 0; i < 8; ++i)
#pragma unroll
        for (int j = 0; j < 4; ++j) acc[i][j] = 0.f;
    for (int kt = 0; kt < K; kt += 32) {
        {
            int r4 = (t & 15) * 4, k2 = t >> 4;
#pragma unroll
            for (int p = 0; p < 2; ++p) {
                int k = k2 + p * 16;
                *(float4*)&At[k][r4] =
                    *(const float4*)&AT[(size_t)(kt + k) * NTOT + row0 + r4];
            }
        }
        {
            int c4 = (t & 31) * 4, kr = t >> 5;
#pragma unroll
            for (int p = 0; p < 4; ++p) {
                int k = kr + p * 8;
                *(float4*)&Wt[k][c4] = *(const float4*)&W[(size_t)(kt + k) * 128 + c4];
            }
        }
        __syncthreads();
#pragma unroll
        for (int k = 0; k < 32; ++k) {
            float4 a0 = *(const float4*)&At[k][ty * 8];
            float4 a1 = *(const float4*)&At[k][ty * 8 + 4];
            float4 w  = *(const float4*)&Wt[k][tx * 4];
            float a[8] = {a0.x, a0.y, a0.z, a0.w, a1.x, a1.y, a1.z, a1.w};
#pragma unroll
            for (int i = 0; i < 8; ++i) {
                acc[i][0] += a[i] * w.x;
                acc[i][1] += a[i] * w.y;
                acc[i][2] += a[i] * w.z;
                acc[i][3] += a[i] * w.w;
            }
        }
        __syncthreads();
    }
    int g = row0 >> 10;
    float b[4];
#pragma unroll
    for (int j = 0; j < 4; ++j) b[j] = bias[tx * 4 + j];
    float gp[4], fr[8];
    if (fvec) {
#pragma unroll
        for (int j = 0; j < 4; ++j) gp[j] = gproj[(size_t)g * 128 + tx * 4 + j];
#pragma unroll
        for (int i = 0; i < 8; ++i) fr[i] = fvec[row0 + ty * 8 + i];
    }
    float w3[4];
    if (zout) {
#pragma unroll
        for (int j = 0; j < 4; ++j) w3[j] = W3[tx * 4 + j];
    }
    float dvs[8];
#pragma unroll
    for (int i = 0; i < 8; ++i) dvs[i] = rsqrtf((float)cnt[row0 + ty * 8 + i] + 1.0f);
    float m[4];
#pragma unroll
    for (int j = 0; j < 4; ++j) m[j] = 0.f;
    float zp[8];
    int cc = tx >> 2, off = (tx & 3) * 4;
#pragma unroll
    for (int i = 0; i < 8; ++i) {
        int r = row0 + ty * 8 + i;
        float o[4];
        float zpi = 0.f;
#pragma unroll
        for (int j = 0; j < 4; ++j) {
            float v = acc[i][j] + b[j];
            if (fvec) v += fr[i] * gp[j];
            v = fmaxf(v, 0.f);
            if (part) m[j] = fmaxf(m[j], v);
            if (zout) zpi += v * w3[j];
            o[j] = v * dvs[i];
        }
        zp[i] = zpi;
        if (outZ)
            *(float4*)&outZ[((size_t)cc * NTOT + r) * 16 + off] =
                make_float4(o[0], o[1], o[2], o[3]);
    }
    if (zout) {
        float* zsm = &At[0][0];
        __syncthreads();
#pragma unroll
        for (int i = 0; i < 8; ++i) zsm[(ty * 8 + i) * 32 + tx] = zp[i];
        __syncthreads();
        if (t < 64) {
            float s = 0.f;
#pragma unroll
            for (int xg = 0; xg < 32; ++xg) s += zsm[t * 32 + xg];
            zout[row0 + t] = s * rsqrtf((float)cnt[row0 + t] + 1.0f);
        }
    }
    if (part) {
        float* sm = &At[0][0];
        __syncthreads();
#pragma unroll
        for (int j = 0; j < 4; ++j) sm[ty * 128 + tx * 4 + j] = m[j];
        __syncthreads();
        for (int s = 4; s >= 1; s >>= 1) {
            if (ty < s) {
#pragma unroll
                for (int j = 0; j < 4; ++j) {
                    int idx = ty * 128 + tx * 4 + j;
                    sm[idx] = fmaxf(sm[idx], sm[(ty + s) * 128 + tx * 4 + j]);
                }
            }
            __syncthreads();
        }
        if (ty == 0) {
            int* pp = (int*)&part[(size_t)g * 128 + tx * 4];
#pragma unroll
            for (int j = 0; j < 4; ++j) atomicMax(pp + j, __float_as_int(sm[tx * 4 + j]));
        }
    }
}

__global__ __launch_bounds__(128) void glob_k(const float* __restrict__ part,
                                              const float* __restrict__ Wf,
                                              const float* __restrict__ bf,
                                              const float* __restrict__ W2,
                                              float* __restrict__ gproj) {
    __shared__ float mp[128];
    __shared__ float gl[128];
    int g = blockIdx.x, t = threadIdx.x;
    mp[t] = part[(size_t)g * 128 + t];
    __syncthreads();
    float acc = bf[t];
    for (int k = 0; k < 128; ++k) acc += mp[k] * Wf[(size_t)k * 128 + t];
    gl[t] = acc;
    __syncthreads();
    float acc2 = 0.f;
    for (int k = 0; k < 128; ++k) acc2 += gl[k] * W2[(size_t)(128 + k) * 128 + t];
    gproj[(size_t)g * 128 + t] = acc2;
}

__global__ __launch_bounds__(256) void smask_k(const float* __restrict__ z,
                                               const unsigned int* __restrict__ colp,
                                               const int* __restrict__ cnt,
                                               const float* __restrict__ b3,
                                               float* __restrict__ out) {
    __shared__ float sz[1024];
    __shared__ float sl[1024];
    __shared__ float slo[1024];
    __shared__ float rv[256];
    __shared__ int   ri[256];
    __shared__ float sth;
    int g = blockIdx.x, t = threadIdx.x;
    int base = g << 10;
#pragma unroll
    for (int i = 0; i < 4; ++i) sz[t + 256 * i] = z[base + t + 256 * i];
    __syncthreads();
    float bb = b3[0];
#pragma unroll 1
    for (int i = 0; i < 4; ++i) {
        int v = t + 256 * i;
        int gv = base + v;
        int n = cnt[gv];
        float dv = rsqrtf((float)n + 1.0f);
        float acc = sz[v];
        const unsigned int* ip = colp + gv;
        int np = n >> 1;
        for (int j = 0; j < np; ++j) {
            unsigned int pw = ip[(size_t)j * NTOT];
            acc += sz[pw & 0xFFFF] + sz[pw >> 16];
        }
        if (n & 1) acc += sz[ip[(size_t)np * NTOT] & 0xFFFF];
        float lg = acc * dv + bb;
        sl[v] = lg; slo[v] = lg;
    }
    __syncthreads();
    for (int pass = 0; pass < KSEL; ++pass) {
        float bv = -INFINITY;
        int bi = 0;
#pragma unroll
        for (int i = 0; i < 4; ++i) {
            float v = sl[t + 256 * i];
            if (v > bv) { bv = v; bi = t + 256 * i; }
        }
        rv[t] = bv; ri[t] = bi;
        __syncthreads();
        for (int s = 128; s > 0; s >>= 1) {
            if (t < s) {
                if (rv[t + s] > rv[t]) { rv[t] = rv[t + s]; ri[t] = ri[t + s]; }
            }
            __syncthreads();
        }
        if (t == 0) { sth = rv[0]; sl[ri[0]] = -INFINITY; }
        __syncthreads();
    }
    float th = sth;
#pragma unroll
    for (int i = 0; i < 4; ++i) {
        int v = t + 256 * i;
        out[base + v] = (slo[v] >= th) ? 1.f : 0.f;
    }
}

// =====================================================================================
extern "C" void kernel_launch(void* const* d_in, const int* in_sizes, int n_in,
                              void* d_out, int out_size, void* d_ws, size_t ws_size,
                              hipStream_t stream) {
    const float* x    = (const float*)d_in[0];
    const int*   esrc = (const int*)d_in[1];
    const int*   edst = (const int*)d_in[2];
    const float* W0 = (const float*)d_in[4];
    const float* b0 = (const float*)d_in[5];
    const float* W1 = (const float*)d_in[6];
    const float* b1 = (const float*)d_in[7];
    const float* Wf = (const float*)d_in[8];
    const float* bf = (const float*)d_in[9];
    const float* W2 = (const float*)d_in[10];
    const float* b2 = (const float*)d_in[11];
    const float* W3 = (const float*)d_in[12];
    const float* b3 = (const float*)d_in[13];
    float* out = (float*)d_out;
    char* ws = (char*)d_ws;

    void* args[] = { &x, &esrc, &edst, &W0, &b0, &W1, &b1, &Wf, &bf,
                     &W2, &b2, &W3, &b3, &out, &ws };
    hipError_t err = hipLaunchCooperativeKernel((const void*)fused_k, dim3(512),
                                                dim3(512), args, 0, stream);
    if (err != hipSuccess) {
        // -------- fallback: proven multi-kernel pipeline (R10) --------
        char* w = ws;
        int*            cnt    = (int*)w;            w += (size_t)NTOT * 4;
        unsigned short* col16  = (unsigned short*)w; w += (size_t)NTOT * MAXDEG * 2;
        float*          fvec   = (float*)w;          w += (size_t)NTOT * 4;
        float*          P      = (float*)w;          w += (size_t)NTOT * 128 * 4;
        float*          Q      = (float*)w;          w += (size_t)NTOT * 128 * 4;
        float*          part   = (float*)w;          w += (size_t)NB * 128 * 4;
        float*          gproj  = (float*)w;          w += (size_t)NB * 128 * 4;
        float*          z      = (float*)w;          w += (size_t)NTOT * 4;
        const unsigned int* colp = (const unsigned int*)col16;

        init_k<<<NTOT / 256, 256, 0, stream>>>(cnt, part);
        csr_k<<<ETOT / 256, 256, 0, stream>>>(esrc, edst, cnt, col16);
        agg_k<<<NB * 4, 1024, 0, stream>>>(nullptr, x, colp, cnt, P, 2, nullptr);
        gemm_k<<<NTOT / 64, 256, 0, stream>>>(P, W0, b0, Q, FEAT, nullptr, nullptr,
                                              part, nullptr, cnt, nullptr);
        glob_k<<<NB, 128, 0, stream>>>(part, Wf, bf, W2, gproj);
        agg_k<<<NB * 8, 1024, 0, stream>>>(Q, nullptr, colp, cnt, P, 3, nullptr);
        gemm_k<<<NTOT / 64, 256, 0, stream>>>(P, W1, b1, Q, HID, nullptr, nullptr,
                                              nullptr, nullptr, cnt, nullptr);
        agg_k<<<NB * 8, 1024, 0, stream>>>(Q, nullptr, colp, cnt, P, 3, nullptr);
        gemm_k<<<NTOT / 64, 256, 0, stream>>>(P, W1, b1, Q, HID, nullptr, nullptr,
                                              nullptr, nullptr, cnt, nullptr);
        agg_k<<<NB * 8, 1024, 0, stream>>>(Q, nullptr, colp, cnt, P, 3, fvec);
        gemm_k<<<NTOT / 64, 256, 0, stream>>>(P, W2, b2, nullptr, HID, fvec, gproj,
                                              nullptr, W3, cnt, z);
        smask_k<<<NB, 256, 0, stream>>>(z, colp, cnt, b3, out);
    }
}